// Round 1
// baseline (39043.274 us; speedup 1.0000x reference)
//
#include <hip/hip_runtime.h>
#include <math.h>

#define TT 400
#define BBATCH 256
#define VDIM 128
#define CDIM 64
#define HDIM 512
#define GDIM 2048
#define KTOT 704
#define KB 32
#define NCHUNK 22
#define BR 64
#define BC 32
#define WCP 580   // padded W_ctrl row stride (577 -> 580, float4-aligned)

__device__ __forceinline__ double sigd(double x) {
  if (x >= 0.0) { double e = exp(-x); return 1.0 / (1.0 + e); }
  double e = exp(x); return e / (1.0 + e);
}

__global__ __launch_bounds__(256) void k_init(
    double* __restrict__ h0, double* __restrict__ cst, double* __restrict__ ybar,
    double* __restrict__ preds, float* __restrict__ halt,
    float* __restrict__ wpad, const float* __restrict__ W_ctrl)
{
  const int i = blockIdx.x * 256 + threadIdx.x;
  if (i < BBATCH * HDIM) { h0[i] = 0.0; cst[i] = 0.0; }
  if (i < BBATCH * CDIM) { ybar[i] = 0.0; preds[i] = 0.0; halt[i] = -1.0f; }
  if (i < CDIM * WCP) {
    const int c = i / WCP, k = i % WCP;
    wpad[i] = (k < 577) ? W_ctrl[c * 577 + k] : 0.0f;
  }
}

// Phase 1: gates = [x_t | ybar | h] @ [W_ih | W_hh].T + b_ih + b_hh, then LSTM cell.
// Grid: x = 64 col-blocks (8 hidden units x 4 gates each), y = 4 row-blocks of 64.
// Wave w handles gate-type w for the block's 8 hidden units, all 64 rows (lane = row).
__global__ __launch_bounds__(256) void k_phase1(
    const float* __restrict__ X, const float* __restrict__ W_ih,
    const float* __restrict__ W_hh, const float* __restrict__ b_ih,
    const float* __restrict__ b_hh, const double* __restrict__ hR,
    double* __restrict__ hW, double* __restrict__ cst,
    const double* __restrict__ ybar, int t)
{
  __shared__ __align__(16) double a_s[KB][BR + 1];   // [k][row], stride 65
  __shared__ __align__(16) double w_s[KB][BC + 2];   // [k][col], stride 34 (even -> b128 reads)
  __shared__ __align__(16) double g_s[4][BR][9];     // gate staging for the cell epilogue

  const int tid   = threadIdx.x;
  const int lane  = tid & 63;
  const int wid   = tid >> 6;          // 0..3 == gate type i,f,g,o
  const int cb    = blockIdx.x;        // 0..63
  const int rb    = blockIdx.y;        // 0..3
  const int r0    = rb * BR;
  const int hbase = cb * (BC / 4);     // 8 hidden units per block

  const int sk = (tid & 7) * 4;        // staging k offset (0,4,...,28)
  const int sr = tid >> 3;             // 0..31: a-row (two halves) / w-col

  double acc[8] = {0,0,0,0,0,0,0,0};
  const int c0 = wid * 8;

  // global W row for staging column sr: gate (sr>>3), hidden hbase+(sr&7)
  const int wg = (sr >> 3) * HDIM + hbase + (sr & 7);

  double pa[2][4];
  float  pw[4];

  auto load_chunk = [&](int ci) {
    const int kb = ci * KB;
    const int kk = kb + sk;
    for (int hf = 0; hf < 2; ++hf) {
      const int rr = r0 + sr + hf * 32;
      if (kk < VDIM) {
        const float4 v = *(const float4*)(X + ((size_t)t * BBATCH + rr) * VDIM + kk);
        pa[hf][0] = v.x; pa[hf][1] = v.y; pa[hf][2] = v.z; pa[hf][3] = v.w;
      } else if (kk < VDIM + CDIM) {
        const double2 v0 = *(const double2*)(ybar + (size_t)rr * CDIM + (kk - VDIM));
        const double2 v1 = *(const double2*)(ybar + (size_t)rr * CDIM + (kk - VDIM) + 2);
        pa[hf][0] = v0.x; pa[hf][1] = v0.y; pa[hf][2] = v1.x; pa[hf][3] = v1.y;
      } else {
        const double2 v0 = *(const double2*)(hR + (size_t)rr * HDIM + (kk - 192));
        const double2 v1 = *(const double2*)(hR + (size_t)rr * HDIM + (kk - 192) + 2);
        pa[hf][0] = v0.x; pa[hf][1] = v0.y; pa[hf][2] = v1.x; pa[hf][3] = v1.y;
      }
    }
    const float4 wv = (kk < 192)
      ? *(const float4*)(W_ih + (size_t)wg * 192 + kk)
      : *(const float4*)(W_hh + (size_t)wg * HDIM + (kk - 192));
    pw[0] = wv.x; pw[1] = wv.y; pw[2] = wv.z; pw[3] = wv.w;
  };

  auto store_chunk = [&]() {
    for (int hf = 0; hf < 2; ++hf)
      for (int j = 0; j < 4; ++j)
        a_s[sk + j][sr + hf * 32] = pa[hf][j];
    for (int j = 0; j < 4; ++j)
      w_s[sk + j][sr] = (double)pw[j];
  };

  load_chunk(0);
  store_chunk();
  __syncthreads();

  for (int ci = 0; ci < NCHUNK; ++ci) {
    if (ci + 1 < NCHUNK) load_chunk(ci + 1);   // in flight under compute
    #pragma unroll
    for (int k = 0; k < KB; ++k) {
      const double av = a_s[k][lane];
      const double2* wp = (const double2*)&w_s[k][c0];
      const double2 w0 = wp[0], w1 = wp[1], w2 = wp[2], w3 = wp[3];
      acc[0] += av * w0.x; acc[1] += av * w0.y;
      acc[2] += av * w1.x; acc[3] += av * w1.y;
      acc[4] += av * w2.x; acc[5] += av * w2.y;
      acc[6] += av * w3.x; acc[7] += av * w3.y;
    }
    __syncthreads();
    if (ci + 1 < NCHUNK) store_chunk();
    __syncthreads();
  }

  // stage gates (+ biases) and run the LSTM cell
  #pragma unroll
  for (int j = 0; j < 8; ++j) {
    const int g = wid * HDIM + hbase + j;
    g_s[wid][lane][j] = acc[j] + (double)b_ih[g] + (double)b_hh[g];
  }
  __syncthreads();

  #pragma unroll
  for (int q = 0; q < 2; ++q) {
    const int j = (tid >> 6) + q * 4;      // 0..7 hidden within block
    const int r = tid & 63;
    const double gi = g_s[0][r][j];
    const double gf = g_s[1][r][j];
    const double gg = g_s[2][r][j];
    const double go = g_s[3][r][j];
    const size_t idx = (size_t)(r0 + r) * HDIM + hbase + j;
    const double cold = cst[idx];
    const double cn = sigd(gf) * cold + sigd(gi) * tanh(gg);
    const double hn = sigd(go) * tanh(cn);
    cst[idx] = cn;
    hW[idx]  = hn;
  }
}

// Phase 2: y_hat, controller probs, halting updates. 64 blocks x 4 waves (1 row/wave).
__global__ __launch_bounds__(256) void k_phase2(
    const double* __restrict__ h, const float* __restrict__ W_out,
    const float* __restrict__ b_out, const float* __restrict__ wpad,
    const float* __restrict__ b_ctrl, const float* __restrict__ noise,
    const int* __restrict__ epoch_p, double* __restrict__ ybar,
    double* __restrict__ preds, float* __restrict__ halt,
    double* __restrict__ ylast, int t)
{
  const int lane = threadIdx.x & 63;
  const int wid  = threadIdx.x >> 6;
  const int b    = blockIdx.x * 4 + wid;
  const double* hrow = h + (size_t)b * HDIM;

  double acc = 0.0;
  const float* wr = W_out + (size_t)lane * HDIM;
  #pragma unroll 4
  for (int k = 0; k < HDIM; k += 4) {
    const float4 w4 = *(const float4*)(wr + k);
    const double2 h0 = *(const double2*)(hrow + k);
    const double2 h1 = *(const double2*)(hrow + k + 2);
    acc += h0.x * (double)w4.x + h0.y * (double)w4.y
         + h1.x * (double)w4.z + h1.y * (double)w4.w;
  }
  const double yh = sigd(acc + (double)b_out[lane]);

  __shared__ double ysh[4][64];
  ysh[wid][lane] = yh;
  __syncthreads();

  double a2 = 0.0;
  const float* wc = wpad + (size_t)lane * WCP;
  #pragma unroll 4
  for (int k = 0; k < HDIM; k += 4) {
    const float4 w4 = *(const float4*)(wc + k);
    const double2 h0 = *(const double2*)(hrow + k);
    const double2 h1 = *(const double2*)(hrow + k + 2);
    a2 += h0.x * (double)w4.x + h0.y * (double)w4.y
        + h1.x * (double)w4.z + h1.y * (double)w4.w;
  }
  #pragma unroll 8
  for (int j = 0; j < CDIM; ++j)
    a2 += ysh[wid][j] * (double)wc[HDIM + j];
  a2 += (double)t * (double)wc[576] + (double)b_ctrl[lane];

  const double eps = exp(-7.0 * (double)(*epoch_p) / 99.0);
  const double pr  = (1.0 - eps) * sigd(a2) + eps * 0.05;
  const double n   = (double)noise[((size_t)t * BBATCH + b) * CDIM + lane];
  const bool   at  = n < pr;

  const size_t i = (size_t)b * CDIM + lane;
  if (at && preds[i] == 0.0) preds[i] = yh;
  if (at && ybar[i]  == 0.0) ybar[i]  = 1.0;
  if (halt[i] == -1.0f && at) halt[i] = (float)t;
  ylast[i] = yh;   // at t==TT-1 this is all_y[-1]
}

__global__ __launch_bounds__(256) void k_final_out(
    const double* __restrict__ preds, const double* __restrict__ ylast,
    float* __restrict__ out)
{
  const int i = blockIdx.x * 256 + threadIdx.x;
  const double p = preds[i];
  out[i] = (float)(p == 0.0 ? ylast[i] : p);
}

__global__ __launch_bounds__(256) void k_final_mean(
    const float* __restrict__ halt, float* __restrict__ out)
{
  __shared__ double s[256];
  double acc = 0.0;
  for (int i = threadIdx.x; i < BBATCH * CDIM; i += 256) {
    const float hp = halt[i];
    acc += 1.0 + (hp == -1.0f ? (double)(TT - 1) : (double)hp);
  }
  s[threadIdx.x] = acc;
  __syncthreads();
  for (int off = 128; off > 0; off >>= 1) {
    if (threadIdx.x < off) s[threadIdx.x] += s[threadIdx.x + off];
    __syncthreads();
  }
  if (threadIdx.x == 0)
    out[BBATCH * CDIM] = (float)(s[0] / (double)(BBATCH * CDIM) / (double)(TT + 1));
}

extern "C" void kernel_launch(void* const* d_in, const int* in_sizes, int n_in,
                              void* d_out, int out_size, void* d_ws, size_t ws_size,
                              hipStream_t stream)
{
  const float* X      = (const float*)d_in[0];
  const float* noise  = (const float*)d_in[1];
  const float* W_ih   = (const float*)d_in[2];
  const float* W_hh   = (const float*)d_in[3];
  const float* b_ih   = (const float*)d_in[4];
  const float* b_hh   = (const float*)d_in[5];
  const float* W_out  = (const float*)d_in[6];
  const float* b_out  = (const float*)d_in[7];
  const float* W_ctrl = (const float*)d_in[8];
  const float* b_ctrl = (const float*)d_in[9];
  const int*   epoch  = (const int*)d_in[10];
  float* out = (float*)d_out;

  char* ws = (char*)d_ws;
  double* h0    = (double*)ws;
  double* h1    = h0    + (size_t)BBATCH * HDIM;
  double* cst   = h1    + (size_t)BBATCH * HDIM;
  double* ybar  = cst   + (size_t)BBATCH * HDIM;
  double* preds = ybar  + (size_t)BBATCH * CDIM;
  double* ylast = preds + (size_t)BBATCH * CDIM;
  float*  halt  = (float*)(ylast + (size_t)BBATCH * CDIM);
  float*  wpad  = halt + (size_t)BBATCH * CDIM;

  k_init<<<512, 256, 0, stream>>>(h0, cst, ybar, preds, halt, wpad, W_ctrl);

  for (int t = 0; t < TT; ++t) {
    const double* hR = (t & 1) ? h1 : h0;
    double*       hW = (t & 1) ? h0 : h1;
    k_phase1<<<dim3(64, 4), 256, 0, stream>>>(X, W_ih, W_hh, b_ih, b_hh,
                                              hR, hW, cst, ybar, t);
    k_phase2<<<64, 256, 0, stream>>>(hW, W_out, b_out, wpad, b_ctrl, noise,
                                     epoch, ybar, preds, halt, ylast, t);
  }

  k_final_out<<<64, 256, 0, stream>>>(preds, ylast, out);
  k_final_mean<<<1, 256, 0, stream>>>(halt, out);
}

// Round 3
// 17006.192 us; speedup vs baseline: 2.2958x; 2.2958x over previous
//
#include <hip/hip_runtime.h>
#include <math.h>

#define TT 400
#define BBATCH 256
#define VDIM 128
#define CDIM 64
#define HDIM 512
#define KTOT 704
#define KB 32
#define NCHUNK 22

typedef double d4 __attribute__((ext_vector_type(4)));

__device__ __forceinline__ double sigd(double x) {
  if (x >= 0.0) { double e = exp(-x); return 1.0 / (1.0 + e); }
  double e = exp(x); return e / (1.0 + e);
}

__global__ __launch_bounds__(256) void k_init(
    double* __restrict__ h0, double* __restrict__ cst, double* __restrict__ ybar,
    double* __restrict__ preds, float* __restrict__ halt,
    float* __restrict__ wtr_out, const float* __restrict__ W_out,
    float* __restrict__ wtrc, const float* __restrict__ W_ctrl)
{
  const int i = blockIdx.x * 256 + threadIdx.x;
  if (i < BBATCH * HDIM) { h0[i] = 0.0; cst[i] = 0.0; }
  if (i < BBATCH * CDIM) { ybar[i] = 0.0; preds[i] = 0.0; halt[i] = -1.0f; }
  if (i < HDIM * CDIM) {                      // W_out (64,512) -> [k][c]
    const int k = i >> 6, c = i & 63;
    wtr_out[i] = W_out[c * HDIM + k];
  }
  if (i < 577 * CDIM) {                       // W_ctrl (64,577) -> [k][c]
    const int k = i >> 6, c = i & 63;
    wtrc[i] = W_ctrl[c * 577 + k];
  }
}

// Phase 1: gates GEMM via f64 MFMA + fused LSTM cell.
// Grid (64,4): 64 col-blocks (8 hidden x 4 gates = 32 gate-cols), 4 row-blocks of 64.
// 4 waves; wave w owns row-tile w (16 rows) x 2 col-tiles of 16.
__global__ __launch_bounds__(256) void k_phase1(
    const float* __restrict__ X, const float* __restrict__ W_ih,
    const float* __restrict__ W_hh, const float* __restrict__ b_ih,
    const float* __restrict__ b_hh, const double* __restrict__ hR,
    double* __restrict__ hW, double* __restrict__ cst,
    const double* __restrict__ ybar, int t)
{
  // fragment-order staging: [buf][rt][s][lane] ; lane l -> row rt*16+(l&15), k 4s+(l>>4)
  __shared__ __align__(16) double aF[2][4][8][64];   // 32 KB
  __shared__ __align__(16) double bF[2][2][8][64];   // 16 KB
  __shared__ __align__(16) double g_s[64][33];       // ~17 KB gate staging

  const int tid   = threadIdx.x;
  const int lane  = tid & 63;
  const int wid   = tid >> 6;
  const int cb    = blockIdx.x;
  const int rb    = blockIdx.y;
  const int r0    = rb * 64;
  const int hbase = cb * 8;

  const int sk = (tid & 7) * 4;     // k offset within chunk (0,4,...,28)
  const int sr = tid >> 3;          // 0..31
  const int s  = sk >> 2;           // k-step slot 0..7
  // W row for staged col sr: gate sr>>3, hidden hbase+(sr&7)
  const int wg = (sr >> 3) * HDIM + hbase + (sr & 7);

  // ---- Empirical D-fragment-layout probe (layout of f64 MFMA D is not
  // trusted): with A lane-layout (row=l&15, k=l>>4) and B (col=l&15, k=l>>4),
  // encode A[i][0]=i+1, A[i][1]=1, B[0][j]=1, B[1][j]=1000(j+1)
  // => D[i][j] = (i+1) + 1000*(j+1). Decode per accumulator register.
  int rowm[4], colm[4];
  {
    d4 dp = {0.0, 0.0, 0.0, 0.0};
    const double ap = (lane < 16) ? (double)(lane + 1) : (lane < 32 ? 1.0 : 0.0);
    const double bp = (lane < 16) ? 1.0
                    : (lane < 32 ? 1000.0 * (double)((lane & 15) + 1) : 0.0);
    dp = __builtin_amdgcn_mfma_f64_16x16x4f64(ap, bp, dp, 0, 0, 0);
    #pragma unroll
    for (int r = 0; r < 4; ++r) {
      const int iv = (int)(dp[r] + 0.5);
      rowm[r] = ((iv % 1000) - 1) & 15;
      colm[r] = ((iv / 1000) - 1) & 15;
    }
  }

  d4 acc0 = {0.0, 0.0, 0.0, 0.0};
  d4 acc1 = {0.0, 0.0, 0.0, 0.0};

  double pa[2][4];
  float  pw[4];

  auto load_chunk = [&](int ci) {
    const int kk = ci * KB + sk;
    for (int hf = 0; hf < 2; ++hf) {
      const int rr = r0 + sr + hf * 32;
      if (kk < VDIM) {
        const float4 v = *(const float4*)(X + ((size_t)t * BBATCH + rr) * VDIM + kk);
        pa[hf][0] = v.x; pa[hf][1] = v.y; pa[hf][2] = v.z; pa[hf][3] = v.w;
      } else if (kk < VDIM + CDIM) {
        const double2 v0 = *(const double2*)(ybar + (size_t)rr * CDIM + (kk - VDIM));
        const double2 v1 = *(const double2*)(ybar + (size_t)rr * CDIM + (kk - VDIM) + 2);
        pa[hf][0] = v0.x; pa[hf][1] = v0.y; pa[hf][2] = v1.x; pa[hf][3] = v1.y;
      } else {
        const double2 v0 = *(const double2*)(hR + (size_t)rr * HDIM + (kk - 192));
        const double2 v1 = *(const double2*)(hR + (size_t)rr * HDIM + (kk - 192) + 2);
        pa[hf][0] = v0.x; pa[hf][1] = v0.y; pa[hf][2] = v1.x; pa[hf][3] = v1.y;
      }
    }
    const float4 wv = (kk < 192)
      ? *(const float4*)(W_ih + (size_t)wg * 192 + kk)
      : *(const float4*)(W_hh + (size_t)wg * HDIM + (kk - 192));
    pw[0] = wv.x; pw[1] = wv.y; pw[2] = wv.z; pw[3] = wv.w;
  };

  auto store_chunk = [&](int buf) {
    for (int hf = 0; hf < 2; ++hf) {
      const int rl = sr + hf * 32;
      const int rt = rl >> 4, rr = rl & 15;
      for (int j = 0; j < 4; ++j)
        aF[buf][rt][s][16 * j + rr] = pa[hf][j];
    }
    const int ct = sr >> 4, cl = sr & 15;
    for (int j = 0; j < 4; ++j)
      bF[buf][ct][s][16 * j + cl] = (double)pw[j];
  };

  load_chunk(0);
  store_chunk(0);
  __syncthreads();

  for (int ci = 0; ci < NCHUNK; ++ci) {
    const int p = ci & 1;
    if (ci + 1 < NCHUNK) load_chunk(ci + 1);   // global loads in flight under MFMA
    #pragma unroll
    for (int ss = 0; ss < 8; ++ss) {
      const double av = aF[p][wid][ss][lane];
      const double b0 = bF[p][0][ss][lane];
      const double b1 = bF[p][1][ss][lane];
      acc0 = __builtin_amdgcn_mfma_f64_16x16x4f64(av, b0, acc0, 0, 0, 0);
      acc1 = __builtin_amdgcn_mfma_f64_16x16x4f64(av, b1, acc1, 0, 0, 0);
    }
    if (ci + 1 < NCHUNK) store_chunk(p ^ 1);   // other buffer: no write-read hazard
    __syncthreads();                            // next chunk ready / this buffer free
  }

  // Stage gates via the probed D layout. Wave wid owns rows 16*wid..16*wid+15;
  // acc0 covers block-cols 0..15, acc1 cols 16..31.
  #pragma unroll
  for (int r = 0; r < 4; ++r) {
    g_s[16 * wid + rowm[r]][colm[r]]      = acc0[r];
    g_s[16 * wid + rowm[r]][16 + colm[r]] = acc1[r];
  }
  __syncthreads();

  // LSTM cell: 512 (row, hidden) pairs, 2 per thread; 8 consecutive lanes = 8
  // consecutive hidden units -> 64B-contiguous global accesses.
  #pragma unroll
  for (int q = 0; q < 2; ++q) {
    const int idx = tid + q * 256;
    const int jj = idx & 7;
    const int r  = idx >> 3;
    const int g0 = hbase + jj;
    const double gi = g_s[r][jj]      + (double)b_ih[0 * HDIM + g0] + (double)b_hh[0 * HDIM + g0];
    const double gf = g_s[r][8 + jj]  + (double)b_ih[1 * HDIM + g0] + (double)b_hh[1 * HDIM + g0];
    const double gg = g_s[r][16 + jj] + (double)b_ih[2 * HDIM + g0] + (double)b_hh[2 * HDIM + g0];
    const double go = g_s[r][24 + jj] + (double)b_ih[3 * HDIM + g0] + (double)b_hh[3 * HDIM + g0];
    const size_t oidx = (size_t)(r0 + r) * HDIM + g0;
    const double cold = cst[oidx];
    const double cn = sigd(gf) * cold + sigd(gi) * tanh(gg);
    const double hn = sigd(go) * tanh(cn);
    cst[oidx] = cn;
    hW[oidx]  = hn;
  }
}

// Phase 2: one batch-row per block; transposed [k][c] weights for coalesced loads.
__global__ __launch_bounds__(256) void k_phase2(
    const double* __restrict__ h, const float* __restrict__ wtr_out,
    const float* __restrict__ b_out, const float* __restrict__ wtrc,
    const float* __restrict__ b_ctrl, const float* __restrict__ noise,
    const int* __restrict__ epoch_p, double* __restrict__ ybar,
    double* __restrict__ preds, float* __restrict__ halt,
    double* __restrict__ ylast, int t)
{
  __shared__ double hsh[HDIM];
  __shared__ double psh[4][64];
  __shared__ double ysh[64];

  const int tid = threadIdx.x;
  const int b   = blockIdx.x;

  *(double2*)&hsh[2 * tid] = *(const double2*)(h + (size_t)b * HDIM + 2 * tid);
  __syncthreads();

  const int c = tid & 63, kq = tid >> 6;
  const int k0 = kq * 128;

  double s1 = 0.0;
  #pragma unroll 8
  for (int k = k0; k < k0 + 128; ++k)
    s1 += hsh[k] * (double)wtr_out[k * 64 + c];
  psh[kq][c] = s1;
  __syncthreads();

  if (tid < 64) {
    const double a1 = psh[0][tid] + psh[1][tid] + psh[2][tid] + psh[3][tid]
                    + (double)b_out[tid];
    ysh[tid] = sigd(a1);
  }
  __syncthreads();

  double s2 = 0.0;
  #pragma unroll 8
  for (int k = k0; k < k0 + 128; ++k)
    s2 += hsh[k] * (double)wtrc[k * 64 + c];
  if (kq == 0) {
    #pragma unroll 8
    for (int j = 0; j < 64; ++j)
      s2 += ysh[j] * (double)wtrc[(512 + j) * 64 + c];
    s2 += (double)t * (double)wtrc[576 * 64 + c] + (double)b_ctrl[c];
  }
  psh[kq][c] = s2;
  __syncthreads();

  if (tid < 64) {
    const double a2 = psh[0][tid] + psh[1][tid] + psh[2][tid] + psh[3][tid];
    const double eps = exp(-7.0 * (double)(*epoch_p) / 99.0);
    const double pr  = (1.0 - eps) * sigd(a2) + eps * 0.05;
    const double n   = (double)noise[((size_t)t * BBATCH + b) * CDIM + tid];
    const bool   at  = n < pr;
    const size_t i   = (size_t)b * CDIM + tid;
    const double yh  = ysh[tid];
    if (at && preds[i] == 0.0) preds[i] = yh;
    if (at && ybar[i]  == 0.0) ybar[i]  = 1.0;
    if (halt[i] == -1.0f && at) halt[i] = (float)t;
    ylast[i] = yh;
  }
}

__global__ __launch_bounds__(256) void k_final_out(
    const double* __restrict__ preds, const double* __restrict__ ylast,
    float* __restrict__ out)
{
  const int i = blockIdx.x * 256 + threadIdx.x;
  const double p = preds[i];
  out[i] = (float)(p == 0.0 ? ylast[i] : p);
}

__global__ __launch_bounds__(256) void k_final_mean(
    const float* __restrict__ halt, float* __restrict__ out)
{
  __shared__ double s[256];
  double acc = 0.0;
  for (int i = threadIdx.x; i < BBATCH * CDIM; i += 256) {
    const float hp = halt[i];
    acc += 1.0 + (hp == -1.0f ? (double)(TT - 1) : (double)hp);
  }
  s[threadIdx.x] = acc;
  __syncthreads();
  for (int off = 128; off > 0; off >>= 1) {
    if (threadIdx.x < off) s[threadIdx.x] += s[threadIdx.x + off];
    __syncthreads();
  }
  if (threadIdx.x == 0)
    out[BBATCH * CDIM] = (float)(s[0] / (double)(BBATCH * CDIM) / (double)(TT + 1));
}

extern "C" void kernel_launch(void* const* d_in, const int* in_sizes, int n_in,
                              void* d_out, int out_size, void* d_ws, size_t ws_size,
                              hipStream_t stream)
{
  const float* X      = (const float*)d_in[0];
  const float* noise  = (const float*)d_in[1];
  const float* W_ih   = (const float*)d_in[2];
  const float* W_hh   = (const float*)d_in[3];
  const float* b_ih   = (const float*)d_in[4];
  const float* b_hh   = (const float*)d_in[5];
  const float* W_out  = (const float*)d_in[6];
  const float* b_out  = (const float*)d_in[7];
  const float* W_ctrl = (const float*)d_in[8];
  const float* b_ctrl = (const float*)d_in[9];
  const int*   epoch  = (const int*)d_in[10];
  float* out = (float*)d_out;

  char* ws = (char*)d_ws;
  double* h0    = (double*)ws;
  double* h1    = h0    + (size_t)BBATCH * HDIM;
  double* cst   = h1    + (size_t)BBATCH * HDIM;
  double* ybar  = cst   + (size_t)BBATCH * HDIM;
  double* preds = ybar  + (size_t)BBATCH * CDIM;
  double* ylast = preds + (size_t)BBATCH * CDIM;
  float*  halt  = (float*)(ylast + (size_t)BBATCH * CDIM);
  float*  wtro  = halt + (size_t)BBATCH * CDIM;
  float*  wtrc  = wtro + (size_t)HDIM * CDIM;

  k_init<<<512, 256, 0, stream>>>(h0, cst, ybar, preds, halt, wtro, W_out, wtrc, W_ctrl);

  for (int t = 0; t < TT; ++t) {
    const double* hR = (t & 1) ? h1 : h0;
    double*       hW = (t & 1) ? h0 : h1;
    k_phase1<<<dim3(64, 4), 256, 0, stream>>>(X, W_ih, W_hh, b_ih, b_hh,
                                              hR, hW, cst, ybar, t);
    k_phase2<<<BBATCH, 256, 0, stream>>>(hW, wtro, b_out, wtrc, b_ctrl, noise,
                                         epoch, ybar, preds, halt, ylast, t);
  }

  k_final_out<<<64, 256, 0, stream>>>(preds, ylast, out);
  k_final_mean<<<1, 256, 0, stream>>>(halt, out);
}

// Round 4
// 6615.752 us; speedup vs baseline: 5.9016x; 2.5706x over previous
//
#include <hip/hip_runtime.h>
#include <math.h>

#define TT 400
#define BBATCH 256
#define VDIM 128
#define CDIM 64
#define HDIM 512
#define KTOT 704
#define KB 32
#define NCHUNK 22

typedef double d4 __attribute__((ext_vector_type(4)));

__device__ __forceinline__ double sigd(double x) {
  if (x >= 0.0) { double e = exp(-x); return 1.0 / (1.0 + e); }
  double e = exp(x); return e / (1.0 + e);
}

__global__ __launch_bounds__(256) void k_init(
    double* __restrict__ h0, double* __restrict__ cst, double* __restrict__ ybar,
    double* __restrict__ preds, float* __restrict__ halt,
    float* __restrict__ wtr_out, const float* __restrict__ W_out,
    float* __restrict__ wtrc, const float* __restrict__ W_ctrl,
    int* __restrict__ alive)
{
  const int i = blockIdx.x * 256 + threadIdx.x;
  if (i < BBATCH * HDIM) { h0[i] = 0.0; cst[i] = 0.0; }
  if (i < BBATCH * CDIM) { ybar[i] = 0.0; preds[i] = 0.0; halt[i] = -1.0f; }
  if (i < TT) alive[i] = 0;
  if (i < HDIM * CDIM) {                      // W_out (64,512) -> [k][c]
    const int k = i >> 6, c = i & 63;
    wtr_out[i] = W_out[c * HDIM + k];
  }
  if (i < 577 * CDIM) {                       // W_ctrl (64,577) -> [k][c]
    const int k = i >> 6, c = i & 63;
    wtrc[i] = W_ctrl[c * 577 + k];
  }
}

// Phase 1: gates GEMM via f64 MFMA + fused LSTM cell.
// Grid (64,4): 64 col-blocks (8 hidden x 4 gates = 32 gate-cols), 4 row-blocks of 64.
__global__ __launch_bounds__(256) void k_phase1(
    const float* __restrict__ X, const float* __restrict__ W_ih,
    const float* __restrict__ W_hh, const float* __restrict__ b_ih,
    const float* __restrict__ b_hh, const double* __restrict__ hR,
    double* __restrict__ hW, double* __restrict__ cst,
    const double* __restrict__ ybar, const int* __restrict__ alive, int t)
{
  // Early exit: once every (b,c) has halted (alive[t-1]==0), h/c no longer
  // influence any output — skip the step entirely.
  if (t > 0 && alive[t - 1] == 0) return;

  // fragment-order staging: [buf][rt][s][lane] ; lane l -> row rt*16+(l&15), k 4s+(l>>4)
  __shared__ __align__(16) double aF[2][4][8][64];   // 32 KB
  __shared__ __align__(16) double bF[2][2][8][64];   // 16 KB
  __shared__ __align__(16) double g_s[64][33];       // ~17 KB gate staging

  const int tid   = threadIdx.x;
  const int lane  = tid & 63;
  const int wid   = tid >> 6;
  const int cb    = blockIdx.x;
  const int rb    = blockIdx.y;
  const int r0    = rb * 64;
  const int hbase = cb * 8;

  const int sk = (tid & 7) * 4;     // k offset within chunk (0,4,...,28)
  const int sr = tid >> 3;          // 0..31
  const int s  = sk >> 2;           // k-step slot 0..7
  // W row for staged col sr: gate sr>>3, hidden hbase+(sr&7)
  const int wg = (sr >> 3) * HDIM + hbase + (sr & 7);

  // ---- Empirical D-fragment-layout probe: with A lane-layout (row=l&15,
  // k=l>>4) and B (col=l&15, k=l>>4), encode A[i][0]=i+1, A[i][1]=1,
  // B[0][j]=1, B[1][j]=1000(j+1) => D[i][j] = (i+1) + 1000*(j+1).
  int rowm[4], colm[4];
  {
    d4 dp = {0.0, 0.0, 0.0, 0.0};
    const double ap = (lane < 16) ? (double)(lane + 1) : (lane < 32 ? 1.0 : 0.0);
    const double bp = (lane < 16) ? 1.0
                    : (lane < 32 ? 1000.0 * (double)((lane & 15) + 1) : 0.0);
    dp = __builtin_amdgcn_mfma_f64_16x16x4f64(ap, bp, dp, 0, 0, 0);
    #pragma unroll
    for (int r = 0; r < 4; ++r) {
      const int iv = (int)(dp[r] + 0.5);
      rowm[r] = ((iv % 1000) - 1) & 15;
      colm[r] = ((iv / 1000) - 1) & 15;
    }
  }

  d4 acc0 = {0.0, 0.0, 0.0, 0.0};
  d4 acc1 = {0.0, 0.0, 0.0, 0.0};

  double pa[2][4];
  float  pw[4];

  auto load_chunk = [&](int ci) {
    const int kk = ci * KB + sk;
    for (int hf = 0; hf < 2; ++hf) {
      const int rr = r0 + sr + hf * 32;
      if (kk < VDIM) {
        const float4 v = *(const float4*)(X + ((size_t)t * BBATCH + rr) * VDIM + kk);
        pa[hf][0] = v.x; pa[hf][1] = v.y; pa[hf][2] = v.z; pa[hf][3] = v.w;
      } else if (kk < VDIM + CDIM) {
        const double2 v0 = *(const double2*)(ybar + (size_t)rr * CDIM + (kk - VDIM));
        const double2 v1 = *(const double2*)(ybar + (size_t)rr * CDIM + (kk - VDIM) + 2);
        pa[hf][0] = v0.x; pa[hf][1] = v0.y; pa[hf][2] = v1.x; pa[hf][3] = v1.y;
      } else {
        const double2 v0 = *(const double2*)(hR + (size_t)rr * HDIM + (kk - 192));
        const double2 v1 = *(const double2*)(hR + (size_t)rr * HDIM + (kk - 192) + 2);
        pa[hf][0] = v0.x; pa[hf][1] = v0.y; pa[hf][2] = v1.x; pa[hf][3] = v1.y;
      }
    }
    const float4 wv = (kk < 192)
      ? *(const float4*)(W_ih + (size_t)wg * 192 + kk)
      : *(const float4*)(W_hh + (size_t)wg * HDIM + (kk - 192));
    pw[0] = wv.x; pw[1] = wv.y; pw[2] = wv.z; pw[3] = wv.w;
  };

  auto store_chunk = [&](int buf) {
    for (int hf = 0; hf < 2; ++hf) {
      const int rl = sr + hf * 32;
      const int rt = rl >> 4, rr = rl & 15;
      for (int j = 0; j < 4; ++j)
        aF[buf][rt][s][16 * j + rr] = pa[hf][j];
    }
    const int ct = sr >> 4, cl = sr & 15;
    for (int j = 0; j < 4; ++j)
      bF[buf][ct][s][16 * j + cl] = (double)pw[j];
  };

  load_chunk(0);
  store_chunk(0);
  __syncthreads();

  for (int ci = 0; ci < NCHUNK; ++ci) {
    const int p = ci & 1;
    if (ci + 1 < NCHUNK) load_chunk(ci + 1);   // global loads in flight under MFMA
    #pragma unroll
    for (int ss = 0; ss < 8; ++ss) {
      const double av = aF[p][wid][ss][lane];
      const double b0 = bF[p][0][ss][lane];
      const double b1 = bF[p][1][ss][lane];
      acc0 = __builtin_amdgcn_mfma_f64_16x16x4f64(av, b0, acc0, 0, 0, 0);
      acc1 = __builtin_amdgcn_mfma_f64_16x16x4f64(av, b1, acc1, 0, 0, 0);
    }
    if (ci + 1 < NCHUNK) store_chunk(p ^ 1);   // other buffer: no write-read hazard
    __syncthreads();                            // next chunk ready / this buffer free
  }

  // Stage gates via the probed D layout. Wave wid owns rows 16*wid..16*wid+15;
  // acc0 covers block-cols 0..15, acc1 cols 16..31.
  #pragma unroll
  for (int r = 0; r < 4; ++r) {
    g_s[16 * wid + rowm[r]][colm[r]]      = acc0[r];
    g_s[16 * wid + rowm[r]][16 + colm[r]] = acc1[r];
  }
  __syncthreads();

  // LSTM cell: 512 (row, hidden) pairs, 2 per thread; 8 consecutive lanes = 8
  // consecutive hidden units -> 64B-contiguous global accesses.
  #pragma unroll
  for (int q = 0; q < 2; ++q) {
    const int idx = tid + q * 256;
    const int jj = idx & 7;
    const int r  = idx >> 3;
    const int g0 = hbase + jj;
    const double gi = g_s[r][jj]      + (double)b_ih[0 * HDIM + g0] + (double)b_hh[0 * HDIM + g0];
    const double gf = g_s[r][8 + jj]  + (double)b_ih[1 * HDIM + g0] + (double)b_hh[1 * HDIM + g0];
    const double gg = g_s[r][16 + jj] + (double)b_ih[2 * HDIM + g0] + (double)b_hh[2 * HDIM + g0];
    const double go = g_s[r][24 + jj] + (double)b_ih[3 * HDIM + g0] + (double)b_hh[3 * HDIM + g0];
    const size_t oidx = (size_t)(r0 + r) * HDIM + g0;
    const double cold = cst[oidx];
    const double cn = sigd(gf) * cold + sigd(gi) * tanh(gg);
    const double hn = sigd(go) * tanh(cn);
    cst[oidx] = cn;
    hW[oidx]  = hn;
  }
}

// Phase 2: one batch-row per block; transposed [k][c] weights for coalesced loads.
__global__ __launch_bounds__(256) void k_phase2(
    const double* __restrict__ h, const float* __restrict__ wtr_out,
    const float* __restrict__ b_out, const float* __restrict__ wtrc,
    const float* __restrict__ b_ctrl, const float* __restrict__ noise,
    const int* __restrict__ epoch_p, double* __restrict__ ybar,
    double* __restrict__ preds, float* __restrict__ halt,
    double* __restrict__ ylast, int* __restrict__ alive, int t)
{
  if (t > 0 && alive[t - 1] == 0) return;

  __shared__ double hsh[HDIM];
  __shared__ double psh[4][64];
  __shared__ double ysh[64];

  const int tid = threadIdx.x;
  const int b   = blockIdx.x;

  *(double2*)&hsh[2 * tid] = *(const double2*)(h + (size_t)b * HDIM + 2 * tid);
  __syncthreads();

  const int c = tid & 63, kq = tid >> 6;
  const int k0 = kq * 128;

  double s1 = 0.0;
  #pragma unroll 8
  for (int k = k0; k < k0 + 128; ++k)
    s1 += hsh[k] * (double)wtr_out[k * 64 + c];
  psh[kq][c] = s1;
  __syncthreads();

  if (tid < 64) {
    const double a1 = psh[0][tid] + psh[1][tid] + psh[2][tid] + psh[3][tid]
                    + (double)b_out[tid];
    ysh[tid] = sigd(a1);
  }
  __syncthreads();

  double s2 = 0.0;
  #pragma unroll 8
  for (int k = k0; k < k0 + 128; ++k)
    s2 += hsh[k] * (double)wtrc[k * 64 + c];
  if (kq == 0) {
    #pragma unroll 8
    for (int j = 0; j < 64; ++j)
      s2 += ysh[j] * (double)wtrc[(512 + j) * 64 + c];
    s2 += (double)t * (double)wtrc[576 * 64 + c] + (double)b_ctrl[c];
  }
  psh[kq][c] = s2;
  __syncthreads();

  bool pz = false;   // this class still unhalted after this step's update?
  if (tid < 64) {
    const double a2 = psh[0][tid] + psh[1][tid] + psh[2][tid] + psh[3][tid];
    const double eps = exp(-7.0 * (double)(*epoch_p) / 99.0);
    const double pr  = (1.0 - eps) * sigd(a2) + eps * 0.05;
    const double n   = (double)noise[((size_t)t * BBATCH + b) * CDIM + tid];
    const bool   at  = n < pr;
    const size_t i   = (size_t)b * CDIM + tid;
    const double yh  = ysh[tid];
    const bool was_zero = (preds[i] == 0.0);
    if (at && was_zero) preds[i] = yh;
    if (at && ybar[i]  == 0.0) ybar[i]  = 1.0;
    if (halt[i] == -1.0f && at) halt[i] = (float)t;
    ylast[i] = yh;
    pz = was_zero && !at;
  }
  const unsigned long long m = __ballot(pz);
  if (tid == 0 && m != 0ull) atomicOr(alive + t, 1);
}

__global__ __launch_bounds__(256) void k_final_out(
    const double* __restrict__ preds, const double* __restrict__ ylast,
    float* __restrict__ out)
{
  const int i = blockIdx.x * 256 + threadIdx.x;
  const double p = preds[i];
  out[i] = (float)(p == 0.0 ? ylast[i] : p);
}

__global__ __launch_bounds__(256) void k_final_mean(
    const float* __restrict__ halt, float* __restrict__ out)
{
  __shared__ double s[256];
  double acc = 0.0;
  for (int i = threadIdx.x; i < BBATCH * CDIM; i += 256) {
    const float hp = halt[i];
    acc += 1.0 + (hp == -1.0f ? (double)(TT - 1) : (double)hp);
  }
  s[threadIdx.x] = acc;
  __syncthreads();
  for (int off = 128; off > 0; off >>= 1) {
    if (threadIdx.x < off) s[threadIdx.x] += s[threadIdx.x + off];
    __syncthreads();
  }
  if (threadIdx.x == 0)
    out[BBATCH * CDIM] = (float)(s[0] / (double)(BBATCH * CDIM) / (double)(TT + 1));
}

extern "C" void kernel_launch(void* const* d_in, const int* in_sizes, int n_in,
                              void* d_out, int out_size, void* d_ws, size_t ws_size,
                              hipStream_t stream)
{
  const float* X      = (const float*)d_in[0];
  const float* noise  = (const float*)d_in[1];
  const float* W_ih   = (const float*)d_in[2];
  const float* W_hh   = (const float*)d_in[3];
  const float* b_ih   = (const float*)d_in[4];
  const float* b_hh   = (const float*)d_in[5];
  const float* W_out  = (const float*)d_in[6];
  const float* b_out  = (const float*)d_in[7];
  const float* W_ctrl = (const float*)d_in[8];
  const float* b_ctrl = (const float*)d_in[9];
  const int*   epoch  = (const int*)d_in[10];
  float* out = (float*)d_out;

  char* ws = (char*)d_ws;
  double* h0    = (double*)ws;
  double* h1    = h0    + (size_t)BBATCH * HDIM;
  double* cst   = h1    + (size_t)BBATCH * HDIM;
  double* ybar  = cst   + (size_t)BBATCH * HDIM;
  double* preds = ybar  + (size_t)BBATCH * CDIM;
  double* ylast = preds + (size_t)BBATCH * CDIM;
  float*  halt  = (float*)(ylast + (size_t)BBATCH * CDIM);
  float*  wtro  = halt + (size_t)BBATCH * CDIM;
  float*  wtrc  = wtro + (size_t)HDIM * CDIM;
  int*    alive = (int*)(wtrc + (size_t)577 * CDIM);

  k_init<<<512, 256, 0, stream>>>(h0, cst, ybar, preds, halt, wtro, W_out,
                                  wtrc, W_ctrl, alive);

  for (int t = 0; t < TT; ++t) {
    const double* hR = (t & 1) ? h1 : h0;
    double*       hW = (t & 1) ? h0 : h1;
    k_phase1<<<dim3(64, 4), 256, 0, stream>>>(X, W_ih, W_hh, b_ih, b_hh,
                                              hR, hW, cst, ybar, alive, t);
    k_phase2<<<BBATCH, 256, 0, stream>>>(hW, wtro, b_out, wtrc, b_ctrl, noise,
                                         epoch, ybar, preds, halt, ylast, alive, t);
  }

  k_final_out<<<64, 256, 0, stream>>>(preds, ylast, out);
  k_final_mean<<<1, 256, 0, stream>>>(halt, out);
}